// Round 1
// baseline (357.309 us; speedup 1.0000x reference)
//
#include <hip/hip_runtime.h>

// ---------------------------------------------------------------------------
// LSTM (T=1, 5 layers, H=32, E=64, B=524288) + final Linear, via f16 MFMA.
//
// Key facts exploited:
//  * T==1, h0=c0=0  =>  w_hh* never used, f-gate never used (c = sig(i)*tanh(g)).
//  * Per-layer weights compacted to 96 rows [i(0:32); g(32:64)->orig 64:96;
//    o(64:96)->orig 96:128].
//  * fp16 hi/lo split, 3 MFMA passes (ah*wh + al*wh + ah*wl): missing term
//    ~2^-22 relative -> effectively fp32-exact.
//
// MFMA 16x16x32 layouts (verified in learn_hip m89/m91/m118-m122):
//   A: lane L holds A[m = L%16][k = 8*(L/16)+j], j=0..7
//   B: lane L holds B[k = 8*(L/16)+j][n = L%16]
//   C/D: lane L reg r holds D[row = (L/16)*4 + r][col = L%16]
// ---------------------------------------------------------------------------

typedef float    f32x4 __attribute__((ext_vector_type(4)));
typedef _Float16 h16x8 __attribute__((ext_vector_type(8)));

#define NBATCH 524288
// ws layout (bytes):
//   [0, 81920)       : 80 weight fragments, 1024 B each (64 lanes x 16 B)
//   [81920, 83840)   : float bias[5][96]  (b_ih + b_hh, compact i/g/o rows)
//   [83840, 84096)   : float fcb[64]
// frag index: layer0: (ntile*2 + kfrag)*2 + s        (ntile 0..5, kfrag 0..1, s=0 hi,1 lo)
//             layer l(1..4): 24 + (l-1)*12 + ntile*2 + s
//             fc:            72 + ntile*2 + s         (ntile 0..3)

__device__ __forceinline__ float sigm(float x) {
    return __builtin_amdgcn_rcpf(1.0f + __expf(-x));
}
__device__ __forceinline__ float tanh_fast(float x) {
    float e = __expf(-2.0f * x);
    return (1.0f - e) * __builtin_amdgcn_rcpf(1.0f + e);
}

__global__ void prep_kernel(const float* __restrict__ w_ih0,
                            const float* __restrict__ w_ih_rest,
                            const float* __restrict__ b_ih,
                            const float* __restrict__ b_hh,
                            const float* __restrict__ fc_w,
                            const float* __restrict__ fc_b,
                            unsigned char* __restrict__ ws)
{
    int t = blockIdx.x * 256 + threadIdx.x;
    if (t < 80 * 64) {
        int f = t >> 6, lane = t & 63;
        int q = lane >> 4, c = lane & 15;
        int layer, ntile, kfrag, s;
        if (f < 24)      { layer = 0;          ntile = f >> 2;        kfrag = (f >> 1) & 1; s = f & 1; }
        else if (f < 72) { int r = f - 24;     layer = 1 + r / 12; r %= 12;
                           ntile = r >> 1;     kfrag = 0;             s = r & 1; }
        else             { int r = f - 72;     layer = 5;
                           ntile = r >> 1;     kfrag = 0;             s = r & 1; }
        int n = ntile * 16 + c;                 // compact gate/output row
        int kbase = kfrag * 32 + q * 8;
        const float* src;
        if (layer == 0)      { int orig = n + (n < 32 ? 0 : 32); src = w_ih0 + orig * 64 + kbase; }
        else if (layer <= 4) { int orig = n + (n < 32 ? 0 : 32);
                               src = w_ih_rest + (((layer - 1) * 128) + orig) * 32 + kbase; }
        else                 { src = fc_w + n * 32 + kbase; }
        h16x8 outv;
        #pragma unroll
        for (int j = 0; j < 8; j++) {
            float v = src[j];
            _Float16 hi = (_Float16)v;
            outv[j] = (s == 0) ? hi : (_Float16)(v - (float)hi);
        }
        ((h16x8*)ws)[f * 64 + lane] = outv;
    } else if (t < 80 * 64 + 480) {
        int idx = t - 80 * 64;
        int l = idx / 96, r = idx % 96;
        int orig = r + (r < 32 ? 0 : 32);
        float* bias = (float*)(ws + 81920);
        bias[idx] = b_ih[l * 128 + orig] + b_hh[l * 128 + orig];
    } else if (t < 80 * 64 + 480 + 64) {
        int e = t - (80 * 64 + 480);
        float* fcb = (float*)(ws + 83840);
        fcb[e] = fc_b[e];
    }
}

__global__ __launch_bounds__(256)
void lstm_mfma(const float* __restrict__ x,
               const unsigned char* __restrict__ ws,
               float* __restrict__ out)
{
    // per-wave private h buffers; row stride 40 (+8 halves pad) -> A-frag reads
    // land 2-way on banks (free), writes at worst 4-way.
    __shared__ __attribute__((aligned(16))) _Float16 hs_hi[4][64][40];
    __shared__ __attribute__((aligned(16))) _Float16 hs_lo[4][64][40];

    const int tid  = threadIdx.x;
    const int wave = tid >> 6;
    const int lane = tid & 63;
    const int q    = lane >> 4;
    const int c    = lane & 15;

    const long batch_base = ((long)blockIdx.x * 4 + wave) * 64;

    const h16x8* wfrag = (const h16x8*)ws;
    const float* biasf = (const float*)(ws + 81920);
    const float* fcbf  = (const float*)(ws + 83840);

    // ---- x -> A-fragments (hi/lo), read straight from global in frag order
    h16x8 xh[4][2], xl[4][2];
    #pragma unroll
    for (int s = 0; s < 4; s++) {
        const float4* xp = (const float4*)(x + (batch_base + s * 16 + c) * 64);
        #pragma unroll
        for (int kf = 0; kf < 2; kf++) {
            float4 a = xp[kf * 8 + q * 2];
            float4 b = xp[kf * 8 + q * 2 + 1];
            float v[8] = {a.x, a.y, a.z, a.w, b.x, b.y, b.z, b.w};
            #pragma unroll
            for (int j = 0; j < 8; j++) {
                _Float16 hi = (_Float16)v[j];
                xh[s][kf][j] = hi;
                xl[s][kf][j] = (_Float16)(v[j] - (float)hi);
            }
        }
    }

    // ---- layer 0 (K=64: 2 k-frags) ----
    #pragma unroll 1
    for (int g2 = 0; g2 < 2; g2++) {          // g2 selects cols [0,16) vs [16,32)
        f32x4 acc[3][4];                       // [i,g,o][subtile]
        #pragma unroll
        for (int kind = 0; kind < 3; kind++) {
            float bv = biasf[kind * 32 + g2 * 16 + c];
            #pragma unroll
            for (int s = 0; s < 4; s++) acc[kind][s] = (f32x4){bv, bv, bv, bv};
        }
        #pragma unroll
        for (int kind = 0; kind < 3; kind++) {
            int nt = kind * 2 + g2;
            #pragma unroll
            for (int kf = 0; kf < 2; kf++) {
                int fr = (nt * 2 + kf) * 2;
                h16x8 wh = wfrag[fr * 64 + lane];
                h16x8 wl = wfrag[fr * 64 + 64 + lane];
                #pragma unroll
                for (int s = 0; s < 4; s++) {
                    acc[kind][s] = __builtin_amdgcn_mfma_f32_16x16x32_f16(xh[s][kf], wh, acc[kind][s], 0, 0, 0);
                    acc[kind][s] = __builtin_amdgcn_mfma_f32_16x16x32_f16(xl[s][kf], wh, acc[kind][s], 0, 0, 0);
                    acc[kind][s] = __builtin_amdgcn_mfma_f32_16x16x32_f16(xh[s][kf], wl, acc[kind][s], 0, 0, 0);
                }
            }
        }
        #pragma unroll
        for (int s = 0; s < 4; s++) {
            #pragma unroll
            for (int r = 0; r < 4; r++) {
                float iv = acc[0][s][r], gv = acc[1][s][r], ov = acc[2][s][r];
                float cv = sigm(iv) * tanh_fast(gv);
                float hv = sigm(ov) * tanh_fast(cv);
                _Float16 hh = (_Float16)hv;
                _Float16 hl = (_Float16)(hv - (float)hh);
                int m = s * 16 + q * 4 + r;
                int col = g2 * 16 + c;
                hs_hi[wave][m][col] = hh;
                hs_lo[wave][m][col] = hl;
            }
        }
    }

    // ---- layers 1..4 (K=32) ----
    #pragma unroll 1
    for (int l = 1; l <= 4; l++) {
        __syncthreads();   // fence LDS writes -> A-frag reads (uniform control flow)
        h16x8 ah[4], al[4];
        #pragma unroll
        for (int s = 0; s < 4; s++) {
            ah[s] = *(const h16x8*)&hs_hi[wave][s * 16 + c][q * 8];
            al[s] = *(const h16x8*)&hs_lo[wave][s * 16 + c][q * 8];
        }
        #pragma unroll 1
        for (int g2 = 0; g2 < 2; g2++) {
            f32x4 acc[3][4];
            #pragma unroll
            for (int kind = 0; kind < 3; kind++) {
                float bv = biasf[l * 96 + kind * 32 + g2 * 16 + c];
                #pragma unroll
                for (int s = 0; s < 4; s++) acc[kind][s] = (f32x4){bv, bv, bv, bv};
            }
            #pragma unroll
            for (int kind = 0; kind < 3; kind++) {
                int nt = kind * 2 + g2;
                int fr = 24 + (l - 1) * 12 + nt * 2;
                h16x8 wh = wfrag[fr * 64 + lane];
                h16x8 wl = wfrag[fr * 64 + 64 + lane];
                #pragma unroll
                for (int s = 0; s < 4; s++) {
                    acc[kind][s] = __builtin_amdgcn_mfma_f32_16x16x32_f16(ah[s], wh, acc[kind][s], 0, 0, 0);
                    acc[kind][s] = __builtin_amdgcn_mfma_f32_16x16x32_f16(al[s], wh, acc[kind][s], 0, 0, 0);
                    acc[kind][s] = __builtin_amdgcn_mfma_f32_16x16x32_f16(ah[s], wl, acc[kind][s], 0, 0, 0);
                }
            }
            #pragma unroll
            for (int s = 0; s < 4; s++) {
                #pragma unroll
                for (int r = 0; r < 4; r++) {
                    float iv = acc[0][s][r], gv = acc[1][s][r], ov = acc[2][s][r];
                    float cv = sigm(iv) * tanh_fast(gv);
                    float hv = sigm(ov) * tanh_fast(cv);
                    _Float16 hh = (_Float16)hv;
                    _Float16 hl = (_Float16)(hv - (float)hh);
                    int m = s * 16 + q * 4 + r;
                    int col = g2 * 16 + c;
                    hs_hi[wave][m][col] = hh;
                    hs_lo[wave][m][col] = hl;
                }
            }
        }
    }

    // ---- fc: out[m][e] = fc_w[e][:] . h5[m][:] + fcb[e]  (N=64 -> 4 n-tiles)
    __syncthreads();
    h16x8 fh[4], fl[4];
    #pragma unroll
    for (int s = 0; s < 4; s++) {
        fh[s] = *(const h16x8*)&hs_hi[wave][s * 16 + c][q * 8];
        fl[s] = *(const h16x8*)&hs_lo[wave][s * 16 + c][q * 8];
    }
    f32x4 acc[4][4];
    #pragma unroll
    for (int t4 = 0; t4 < 4; t4++) {
        float bv = fcbf[t4 * 16 + c];
        #pragma unroll
        for (int s = 0; s < 4; s++) acc[t4][s] = (f32x4){bv, bv, bv, bv};
    }
    #pragma unroll
    for (int t4 = 0; t4 < 4; t4++) {
        int fr = 72 + t4 * 2;
        h16x8 wh = wfrag[fr * 64 + lane];
        h16x8 wl = wfrag[fr * 64 + 64 + lane];
        #pragma unroll
        for (int s = 0; s < 4; s++) {
            acc[t4][s] = __builtin_amdgcn_mfma_f32_16x16x32_f16(fh[s], wh, acc[t4][s], 0, 0, 0);
            acc[t4][s] = __builtin_amdgcn_mfma_f32_16x16x32_f16(fl[s], wh, acc[t4][s], 0, 0, 0);
            acc[t4][s] = __builtin_amdgcn_mfma_f32_16x16x32_f16(fh[s], wl, acc[t4][s], 0, 0, 0);
        }
    }
    // store: per (t4,s,r) instr, 16 c-lanes are 64B-contiguous x 4 quads -> dense
    #pragma unroll
    for (int t4 = 0; t4 < 4; t4++) {
        #pragma unroll
        for (int s = 0; s < 4; s++) {
            #pragma unroll
            for (int r = 0; r < 4; r++) {
                long row = batch_base + s * 16 + q * 4 + r;
                out[row * 64 + t4 * 16 + c] = acc[t4][s][r];
            }
        }
    }
}

extern "C" void kernel_launch(void* const* d_in, const int* in_sizes, int n_in,
                              void* d_out, int out_size, void* d_ws, size_t ws_size,
                              hipStream_t stream)
{
    const float* x         = (const float*)d_in[0];
    const float* w_ih0     = (const float*)d_in[1];
    // d_in[2] = w_hh0   : unused (h0 == 0)
    const float* w_ih_rest = (const float*)d_in[3];
    // d_in[4] = w_hh_rest: unused
    const float* b_ih      = (const float*)d_in[5];
    const float* b_hh      = (const float*)d_in[6];
    const float* fc_w      = (const float*)d_in[7];
    const float* fc_b      = (const float*)d_in[8];
    unsigned char* ws      = (unsigned char*)d_ws;
    float* out             = (float*)d_out;

    // d_ws is re-poisoned before every launch -> prep must run every call.
    prep_kernel<<<23, 256, 0, stream>>>(w_ih0, w_ih_rest, b_ih, b_hh, fc_w, fc_b, ws);

    // 524288 batch / (4 waves * 64 rows) = 2048 blocks
    lstm_mfma<<<2048, 256, 0, stream>>>(x, ws, out);
}

// Round 2
// 303.503 us; speedup vs baseline: 1.1773x; 1.1773x over previous
//
#include <hip/hip_runtime.h>

// ---------------------------------------------------------------------------
// LSTM (T=1, 5 layers, H=32, E=64, B=524288) + final Linear, via f16 MFMA.
//
//  * T==1, h0=c0=0  =>  w_hh* never used, f-gate never used (c = sig(i)*tanh(g)).
//  * Layer 0: x split hi/lo f16, 3 MFMA passes (xh*wh + xl*wh + xh*wl) ~ fp32.
//  * Layers 1-4 + fc: h stored as single f16 (|h|<1, quant err 2.4e-4 ->
//    ~1e-4 per gate), 2 MFMA passes (ah*wh + ah*wl) keep weights ~exact.
//  * 32 batch rows per wave (2 m-subtiles): acc = 24 regs, x-frags = 32 regs
//    -> higher occupancy than the 64-row variant (was ~140 vgpr+agpr).
//  * Per-wave-private LDS h buffer; wave_barrier (free) instead of
//    __syncthreads so waves stay decoupled.
//
// MFMA 16x16x32 layouts:
//   A: lane L holds A[m = L%16][k = 8*(L/16)+j], j=0..7
//   B: lane L holds B[k = 8*(L/16)+j][n = L%16]
//   C/D: lane L reg r holds D[row = (L/16)*4 + r][col = L%16]
// ---------------------------------------------------------------------------

typedef float    f32x4 __attribute__((ext_vector_type(4)));
typedef _Float16 h16x8 __attribute__((ext_vector_type(8)));

// ws layout (bytes):
//   [0, 81920)       : 80 weight fragments, 1024 B each (64 lanes x 16 B)
//   [81920, 83840)   : float bias[5][96]  (b_ih + b_hh, compact i/g/o rows)
//   [83840, 84096)   : float fcb[64]

__device__ __forceinline__ float lstm_act(float iv, float gv, float ov) {
    // h = sigmoid(o) * tanh( sigmoid(i) * tanh(g) ), fused-rcp form:
    float a  = __expf(-iv);
    float b  = __expf(-2.0f * gv);
    float cc = (1.0f - b) * __builtin_amdgcn_rcpf((1.0f + a) * (1.0f + b));
    float d  = __expf(-ov);
    float f  = __expf(-2.0f * cc);
    return (1.0f - f) * __builtin_amdgcn_rcpf((1.0f + d) * (1.0f + f));
}

__global__ void prep_kernel(const float* __restrict__ w_ih0,
                            const float* __restrict__ w_ih_rest,
                            const float* __restrict__ b_ih,
                            const float* __restrict__ b_hh,
                            const float* __restrict__ fc_w,
                            const float* __restrict__ fc_b,
                            unsigned char* __restrict__ ws)
{
    int t = blockIdx.x * 256 + threadIdx.x;
    if (t < 80 * 64) {
        int f = t >> 6, lane = t & 63;
        int q = lane >> 4, c = lane & 15;
        int layer, ntile, kfrag, s;
        if (f < 24)      { layer = 0;          ntile = f >> 2;        kfrag = (f >> 1) & 1; s = f & 1; }
        else if (f < 72) { int r = f - 24;     layer = 1 + r / 12; r %= 12;
                           ntile = r >> 1;     kfrag = 0;             s = r & 1; }
        else             { int r = f - 72;     layer = 5;
                           ntile = r >> 1;     kfrag = 0;             s = r & 1; }
        int n = ntile * 16 + c;                 // compact gate/output row
        int kbase = kfrag * 32 + q * 8;
        const float* src;
        if (layer == 0)      { int orig = n + (n < 32 ? 0 : 32); src = w_ih0 + orig * 64 + kbase; }
        else if (layer <= 4) { int orig = n + (n < 32 ? 0 : 32);
                               src = w_ih_rest + (((layer - 1) * 128) + orig) * 32 + kbase; }
        else                 { src = fc_w + n * 32 + kbase; }
        h16x8 outv;
        #pragma unroll
        for (int j = 0; j < 8; j++) {
            float v = src[j];
            _Float16 hi = (_Float16)v;
            outv[j] = (s == 0) ? hi : (_Float16)(v - (float)hi);
        }
        ((h16x8*)ws)[f * 64 + lane] = outv;
    } else if (t < 80 * 64 + 480) {
        int idx = t - 80 * 64;
        int l = idx / 96, r = idx % 96;
        int orig = r + (r < 32 ? 0 : 32);
        float* bias = (float*)(ws + 81920);
        bias[idx] = b_ih[l * 128 + orig] + b_hh[l * 128 + orig];
    } else if (t < 80 * 64 + 480 + 64) {
        int e = t - (80 * 64 + 480);
        float* fcb = (float*)(ws + 83840);
        fcb[e] = fc_b[e];
    }
}

__global__ __launch_bounds__(256)
void lstm_mfma(const float* __restrict__ x,
               const unsigned char* __restrict__ ws,
               float* __restrict__ out)
{
    // per-wave private h buffer, f16 only; row stride 40 halves (80 B) keeps
    // b128 A-frag reads 16B-aligned and 2-way-max on banks (free).
    __shared__ __attribute__((aligned(16))) _Float16 hs[4][32][40];

    const int tid  = threadIdx.x;
    const int wave = tid >> 6;
    const int lane = tid & 63;
    const int q    = lane >> 4;
    const int c    = lane & 15;

    const long batch_base = ((long)blockIdx.x * 4 + wave) * 32;

    const h16x8* wfrag = (const h16x8*)ws;
    const float* biasf = (const float*)(ws + 81920);
    const float* fcbf  = (const float*)(ws + 83840);

    // ---- x -> A-fragments (hi/lo), read straight from global in frag order
    h16x8 xh[2][2], xl[2][2];
    #pragma unroll
    for (int s = 0; s < 2; s++) {
        const float4* xp = (const float4*)(x + (batch_base + s * 16 + c) * 64);
        #pragma unroll
        for (int kf = 0; kf < 2; kf++) {
            float4 a = xp[kf * 8 + q * 2];
            float4 b = xp[kf * 8 + q * 2 + 1];
            float v[8] = {a.x, a.y, a.z, a.w, b.x, b.y, b.z, b.w};
            #pragma unroll
            for (int j = 0; j < 8; j++) {
                _Float16 hi = (_Float16)v[j];
                xh[s][kf][j] = hi;
                xl[s][kf][j] = (_Float16)(v[j] - (float)hi);
            }
        }
    }

    // ---- layer 0 (K=64: 2 k-frags, 3 passes) ----
    #pragma unroll 1
    for (int g2 = 0; g2 < 2; g2++) {          // g2 selects cols [0,16) vs [16,32)
        f32x4 acc[3][2];                       // [i,g,o][subtile]
        #pragma unroll
        for (int kind = 0; kind < 3; kind++) {
            float bv = biasf[kind * 32 + g2 * 16 + c];
            #pragma unroll
            for (int s = 0; s < 2; s++) acc[kind][s] = (f32x4){bv, bv, bv, bv};
        }
        #pragma unroll
        for (int kind = 0; kind < 3; kind++) {
            int nt = kind * 2 + g2;
            #pragma unroll
            for (int kf = 0; kf < 2; kf++) {
                int fr = (nt * 2 + kf) * 2;
                h16x8 wh = wfrag[fr * 64 + lane];
                h16x8 wl = wfrag[fr * 64 + 64 + lane];
                #pragma unroll
                for (int s = 0; s < 2; s++) {
                    acc[kind][s] = __builtin_amdgcn_mfma_f32_16x16x32_f16(xh[s][kf], wh, acc[kind][s], 0, 0, 0);
                    acc[kind][s] = __builtin_amdgcn_mfma_f32_16x16x32_f16(xl[s][kf], wh, acc[kind][s], 0, 0, 0);
                    acc[kind][s] = __builtin_amdgcn_mfma_f32_16x16x32_f16(xh[s][kf], wl, acc[kind][s], 0, 0, 0);
                }
            }
        }
        #pragma unroll
        for (int s = 0; s < 2; s++) {
            #pragma unroll
            for (int r = 0; r < 4; r++) {
                float hv = lstm_act(acc[0][s][r], acc[1][s][r], acc[2][s][r]);
                hs[wave][s * 16 + q * 4 + r][g2 * 16 + c] = (_Float16)hv;
            }
        }
    }

    // ---- layers 1..4 (K=32, 2 passes, f16 h) ----
    #pragma unroll 1
    for (int l = 1; l <= 4; l++) {
        __builtin_amdgcn_wave_barrier();   // order prev writes before reads (per-wave LDS)
        h16x8 ah[2];
        #pragma unroll
        for (int s = 0; s < 2; s++)
            ah[s] = *(const h16x8*)&hs[wave][s * 16 + c][q * 8];
        __builtin_amdgcn_wave_barrier();   // order reads before this layer's writes
        #pragma unroll 1
        for (int g2 = 0; g2 < 2; g2++) {
            f32x4 acc[3][2];
            #pragma unroll
            for (int kind = 0; kind < 3; kind++) {
                float bv = biasf[l * 96 + kind * 32 + g2 * 16 + c];
                #pragma unroll
                for (int s = 0; s < 2; s++) acc[kind][s] = (f32x4){bv, bv, bv, bv};
            }
            #pragma unroll
            for (int kind = 0; kind < 3; kind++) {
                int nt = kind * 2 + g2;
                int fr = 24 + (l - 1) * 12 + nt * 2;
                h16x8 wh = wfrag[fr * 64 + lane];
                h16x8 wl = wfrag[fr * 64 + 64 + lane];
                #pragma unroll
                for (int s = 0; s < 2; s++) {
                    acc[kind][s] = __builtin_amdgcn_mfma_f32_16x16x32_f16(ah[s], wh, acc[kind][s], 0, 0, 0);
                    acc[kind][s] = __builtin_amdgcn_mfma_f32_16x16x32_f16(ah[s], wl, acc[kind][s], 0, 0, 0);
                }
            }
            #pragma unroll
            for (int s = 0; s < 2; s++) {
                #pragma unroll
                for (int r = 0; r < 4; r++) {
                    float hv = lstm_act(acc[0][s][r], acc[1][s][r], acc[2][s][r]);
                    hs[wave][s * 16 + q * 4 + r][g2 * 16 + c] = (_Float16)hv;
                }
            }
        }
    }

    // ---- fc: out[m][e] = fc_w[e][:] . h5[m][:] + fcb[e]  (N=64 -> 4 n-tiles)
    __builtin_amdgcn_wave_barrier();
    h16x8 fh[2];
    #pragma unroll
    for (int s = 0; s < 2; s++)
        fh[s] = *(const h16x8*)&hs[wave][s * 16 + c][q * 8];

    #pragma unroll 1
    for (int t4 = 0; t4 < 4; t4++) {
        f32x4 acc[2];
        float bv = fcbf[t4 * 16 + c];
        #pragma unroll
        for (int s = 0; s < 2; s++) acc[s] = (f32x4){bv, bv, bv, bv};
        int fr = 72 + t4 * 2;
        h16x8 wh = wfrag[fr * 64 + lane];
        h16x8 wl = wfrag[fr * 64 + 64 + lane];
        #pragma unroll
        for (int s = 0; s < 2; s++) {
            acc[s] = __builtin_amdgcn_mfma_f32_16x16x32_f16(fh[s], wh, acc[s], 0, 0, 0);
            acc[s] = __builtin_amdgcn_mfma_f32_16x16x32_f16(fh[s], wl, acc[s], 0, 0, 0);
        }
        // store: 16 c-lanes 64B-contiguous per (s,r); 4 q-quads on distinct rows
        #pragma unroll
        for (int s = 0; s < 2; s++) {
            #pragma unroll
            for (int r = 0; r < 4; r++) {
                long row = batch_base + s * 16 + q * 4 + r;
                out[row * 64 + t4 * 16 + c] = acc[s][r];
            }
        }
    }
}

extern "C" void kernel_launch(void* const* d_in, const int* in_sizes, int n_in,
                              void* d_out, int out_size, void* d_ws, size_t ws_size,
                              hipStream_t stream)
{
    const float* x         = (const float*)d_in[0];
    const float* w_ih0     = (const float*)d_in[1];
    // d_in[2] = w_hh0    : unused (h0 == 0)
    const float* w_ih_rest = (const float*)d_in[3];
    // d_in[4] = w_hh_rest: unused
    const float* b_ih      = (const float*)d_in[5];
    const float* b_hh      = (const float*)d_in[6];
    const float* fc_w      = (const float*)d_in[7];
    const float* fc_b      = (const float*)d_in[8];
    unsigned char* ws      = (unsigned char*)d_ws;
    float* out             = (float*)d_out;

    // d_ws is re-poisoned before every launch -> prep must run every call.
    prep_kernel<<<23, 256, 0, stream>>>(w_ih0, w_ih_rest, b_ih, b_hh, fc_w, fc_b, ws);

    // 524288 batch / (4 waves * 32 rows) = 4096 blocks
    lstm_mfma<<<4096, 256, 0, stream>>>(x, ws, out);
}

// Round 3
// 299.969 us; speedup vs baseline: 1.1912x; 1.0118x over previous
//
#include <hip/hip_runtime.h>

// ---------------------------------------------------------------------------
// LSTM (T=1, 5 layers, H=32, E=64, B=524288) + final Linear, via f16 MFMA.
//
//  * T==1, h0=c0=0  =>  w_hh* never used, f-gate never used (c = sig(i)*tanh(g)).
//  * Inputs (x, h) stored as single f16 (RNE); weights kept hi/lo 2-pass ->
//    weight quant ~exact, input quant ~1e-4 effect. absmax budget 5.6e-3.
//  * exp2-domain gates: prep folds -log2e (i,o rows) / -2log2e (g rows) into
//    weights+biases, so activation uses raw v_exp_f32 (exp2), no arg muls.
//  * tanh(c), c in (-1,1), via Pade[5/4]: c*(945+105z+z^2)/(945+420z+15z^2),
//    z=c^2 (err ~5e-8); denominator folded into sigmoid(o)'s rcp ->
//    act = 3 exp2 + 2 rcp total.
//  * fc fragments use col map n=4c+t4 -> 4 contiguous out cols per lane ->
//    float4 stores.
//
// MFMA 16x16x32 layouts:
//   A: lane L holds A[m = L%16][k = 8*(L/16)+j], j=0..7
//   B: lane L holds B[k = 8*(L/16)+j][n = L%16]
//   C/D: lane L reg r holds D[row = (L/16)*4 + r][col = L%16]
// ---------------------------------------------------------------------------

typedef float    f32x4 __attribute__((ext_vector_type(4)));
typedef _Float16 h16x8 __attribute__((ext_vector_type(8)));

// ws layout (bytes):
//   [0, 81920)       : 80 weight fragments, 1024 B each (64 lanes x 16 B)
//   [81920, 83840)   : float bias[5][96]  (scaled, compact i/g/o rows)
//   [83840, 84096)   : float fcb[64]

#define LOG2E   1.4426950408889634f

__device__ __forceinline__ float lstm_act(float gi, float gg, float go) {
    // gi = -i*log2e, gg = -2g*log2e, go = -o*log2e (folded into weights)
    float a  = __builtin_amdgcn_exp2f(gi);             // e^-i
    float b  = __builtin_amdgcn_exp2f(gg);             // e^-2g
    float cc = (1.0f - b) * __builtin_amdgcn_rcpf((1.0f + a) * (1.0f + b));
    float z  = cc * cc;
    float N  = __builtin_fmaf(z, z + 105.0f, 945.0f);                      // z^2+105z+945
    float D  = __builtin_fmaf(z, __builtin_fmaf(z, 15.0f, 420.0f), 945.0f);// 15z^2+420z+945
    float d  = __builtin_amdgcn_exp2f(go);             // e^-o
    return (cc * N) * __builtin_amdgcn_rcpf((1.0f + d) * D);
}

__global__ void prep_kernel(const float* __restrict__ w_ih0,
                            const float* __restrict__ w_ih_rest,
                            const float* __restrict__ b_ih,
                            const float* __restrict__ b_hh,
                            const float* __restrict__ fc_w,
                            const float* __restrict__ fc_b,
                            unsigned char* __restrict__ ws)
{
    int t = blockIdx.x * 256 + threadIdx.x;
    if (t < 80 * 64) {
        int f = t >> 6, lane = t & 63;
        int q = lane >> 4, c = lane & 15;
        int layer, ntile, kfrag, s;
        if (f < 24)      { layer = 0;          ntile = f >> 2;        kfrag = (f >> 1) & 1; s = f & 1; }
        else if (f < 72) { int r = f - 24;     layer = 1 + r / 12; r %= 12;
                           ntile = r >> 1;     kfrag = 0;             s = r & 1; }
        else             { int r = f - 72;     layer = 5;
                           ntile = r >> 1;     kfrag = 0;             s = r & 1; }
        int kbase = kfrag * 32 + q * 8;
        const float* src;
        float scale;
        if (layer <= 4) {
            int n = ntile * 16 + c;             // compact gate row: i[0,32) g[32,64) o[64,96)
            int orig = n + (n < 32 ? 0 : 32);
            scale = (n >= 32 && n < 64) ? -2.0f * LOG2E : -LOG2E;
            src = (layer == 0) ? (w_ih0 + orig * 64 + kbase)
                               : (w_ih_rest + (((layer - 1) * 128) + orig) * 32 + kbase);
        } else {
            int n = 4 * c + ntile;              // fc col remap for float4 stores
            scale = 1.0f;
            src = fc_w + n * 32 + kbase;
        }
        h16x8 outv;
        #pragma unroll
        for (int j = 0; j < 8; j++) {
            float v = src[j] * scale;
            _Float16 hi = (_Float16)v;
            outv[j] = (s == 0) ? hi : (_Float16)(v - (float)hi);
        }
        ((h16x8*)ws)[f * 64 + lane] = outv;
    } else if (t < 80 * 64 + 480) {
        int idx = t - 80 * 64;
        int l = idx / 96, r = idx % 96;
        int orig = r + (r < 32 ? 0 : 32);
        float scale = (r >= 32 && r < 64) ? -2.0f * LOG2E : -LOG2E;
        float* bias = (float*)(ws + 81920);
        bias[idx] = (b_ih[l * 128 + orig] + b_hh[l * 128 + orig]) * scale;
    } else if (t < 80 * 64 + 480 + 64) {
        int e = t - (80 * 64 + 480);
        float* fcb = (float*)(ws + 83840);
        fcb[e] = fc_b[e];
    }
}

__global__ __launch_bounds__(256)
void lstm_mfma(const float* __restrict__ x,
               const unsigned char* __restrict__ ws,
               float* __restrict__ out)
{
    // per-wave private h buffer; row stride 40 halves (80 B = 16B-aligned)
    __shared__ __attribute__((aligned(16))) _Float16 hs[4][32][40];

    const int tid  = threadIdx.x;
    const int wave = tid >> 6;
    const int lane = tid & 63;
    const int q    = lane >> 4;
    const int c    = lane & 15;

    const long batch_base = ((long)blockIdx.x * 4 + wave) * 32;

    const h16x8* wfrag = (const h16x8*)ws;
    const float* biasf = (const float*)(ws + 81920);
    const float* fcbf  = (const float*)(ws + 83840);

    // ---- x -> A-fragments, single f16 (RNE casts keep quant unbiased)
    h16x8 xh[2][2];
    #pragma unroll
    for (int s = 0; s < 2; s++) {
        const float4* xp = (const float4*)(x + (batch_base + s * 16 + c) * 64);
        #pragma unroll
        for (int kf = 0; kf < 2; kf++) {
            float4 a = xp[kf * 8 + q * 2];
            float4 b = xp[kf * 8 + q * 2 + 1];
            float v[8] = {a.x, a.y, a.z, a.w, b.x, b.y, b.z, b.w};
            #pragma unroll
            for (int j = 0; j < 8; j++) xh[s][kf][j] = (_Float16)v[j];
        }
    }

    // ---- layer 0 (K=64: 2 k-frags; passes xh*wh + xh*wl) ----
    #pragma unroll 1
    for (int g2 = 0; g2 < 2; g2++) {
        f32x4 acc[3][2];
        #pragma unroll
        for (int kind = 0; kind < 3; kind++) {
            float bv = biasf[kind * 32 + g2 * 16 + c];
            #pragma unroll
            for (int s = 0; s < 2; s++) acc[kind][s] = (f32x4){bv, bv, bv, bv};
        }
        #pragma unroll
        for (int kind = 0; kind < 3; kind++) {
            int nt = kind * 2 + g2;
            #pragma unroll
            for (int kf = 0; kf < 2; kf++) {
                int fr = (nt * 2 + kf) * 2;
                h16x8 wh = wfrag[fr * 64 + lane];
                h16x8 wl = wfrag[fr * 64 + 64 + lane];
                #pragma unroll
                for (int s = 0; s < 2; s++) {
                    acc[kind][s] = __builtin_amdgcn_mfma_f32_16x16x32_f16(xh[s][kf], wh, acc[kind][s], 0, 0, 0);
                    acc[kind][s] = __builtin_amdgcn_mfma_f32_16x16x32_f16(xh[s][kf], wl, acc[kind][s], 0, 0, 0);
                }
            }
        }
        #pragma unroll
        for (int s = 0; s < 2; s++) {
            #pragma unroll
            for (int r = 0; r < 4; r++) {
                float hv = lstm_act(acc[0][s][r], acc[1][s][r], acc[2][s][r]);
                hs[wave][s * 16 + q * 4 + r][g2 * 16 + c] = (_Float16)hv;
            }
        }
    }

    // ---- layers 1..4 (K=32; passes ah*wh + ah*wl) ----
    #pragma unroll 1
    for (int l = 1; l <= 4; l++) {
        __builtin_amdgcn_wave_barrier();   // order prev writes before reads (per-wave LDS)
        h16x8 ah[2];
        #pragma unroll
        for (int s = 0; s < 2; s++)
            ah[s] = *(const h16x8*)&hs[wave][s * 16 + c][q * 8];
        __builtin_amdgcn_wave_barrier();   // order reads before this layer's writes
        #pragma unroll 1
        for (int g2 = 0; g2 < 2; g2++) {
            f32x4 acc[3][2];
            #pragma unroll
            for (int kind = 0; kind < 3; kind++) {
                float bv = biasf[l * 96 + kind * 32 + g2 * 16 + c];
                #pragma unroll
                for (int s = 0; s < 2; s++) acc[kind][s] = (f32x4){bv, bv, bv, bv};
            }
            #pragma unroll
            for (int kind = 0; kind < 3; kind++) {
                int fr = 24 + (l - 1) * 12 + (kind * 2 + g2) * 2;
                h16x8 wh = wfrag[fr * 64 + lane];
                h16x8 wl = wfrag[fr * 64 + 64 + lane];
                #pragma unroll
                for (int s = 0; s < 2; s++) {
                    acc[kind][s] = __builtin_amdgcn_mfma_f32_16x16x32_f16(ah[s], wh, acc[kind][s], 0, 0, 0);
                    acc[kind][s] = __builtin_amdgcn_mfma_f32_16x16x32_f16(ah[s], wl, acc[kind][s], 0, 0, 0);
                }
            }
            #pragma unroll
            for (int s = 0; s < 2; s++) {
                #pragma unroll
                for (int r = 0; r < 4; r++) {
                    float hv = lstm_act(acc[0][s][r], acc[1][s][r], acc[2][s][r]);
                    hs[wave][s * 16 + q * 4 + r][g2 * 16 + c] = (_Float16)hv;
                }
            }
        }
    }

    // ---- fc: out[m][4c+t4] ; all 4 n-tiles live -> float4 stores ----
    __builtin_amdgcn_wave_barrier();
    h16x8 fh[2];
    #pragma unroll
    for (int s = 0; s < 2; s++)
        fh[s] = *(const h16x8*)&hs[wave][s * 16 + c][q * 8];

    f32x4 acc[4][2];
    #pragma unroll
    for (int t4 = 0; t4 < 4; t4++) {
        float bv = fcbf[4 * c + t4];
        #pragma unroll
        for (int s = 0; s < 2; s++) acc[t4][s] = (f32x4){bv, bv, bv, bv};
    }
    #pragma unroll
    for (int t4 = 0; t4 < 4; t4++) {
        int fr = 72 + t4 * 2;
        h16x8 wh = wfrag[fr * 64 + lane];
        h16x8 wl = wfrag[fr * 64 + 64 + lane];
        #pragma unroll
        for (int s = 0; s < 2; s++) {
            acc[t4][s] = __builtin_amdgcn_mfma_f32_16x16x32_f16(fh[s], wh, acc[t4][s], 0, 0, 0);
            acc[t4][s] = __builtin_amdgcn_mfma_f32_16x16x32_f16(fh[s], wl, acc[t4][s], 0, 0, 0);
        }
    }
    #pragma unroll
    for (int s = 0; s < 2; s++) {
        #pragma unroll
        for (int r = 0; r < 4; r++) {
            long row = batch_base + s * 16 + q * 4 + r;
            float4 o4 = {acc[0][s][r], acc[1][s][r], acc[2][s][r], acc[3][s][r]};
            *(float4*)(out + row * 64 + 4 * c) = o4;
        }
    }
}

extern "C" void kernel_launch(void* const* d_in, const int* in_sizes, int n_in,
                              void* d_out, int out_size, void* d_ws, size_t ws_size,
                              hipStream_t stream)
{
    const float* x         = (const float*)d_in[0];
    const float* w_ih0     = (const float*)d_in[1];
    // d_in[2] = w_hh0    : unused (h0 == 0)
    const float* w_ih_rest = (const float*)d_in[3];
    // d_in[4] = w_hh_rest: unused
    const float* b_ih      = (const float*)d_in[5];
    const float* b_hh      = (const float*)d_in[6];
    const float* fc_w      = (const float*)d_in[7];
    const float* fc_b      = (const float*)d_in[8];
    unsigned char* ws      = (unsigned char*)d_ws;
    float* out             = (float*)d_out;

    // d_ws is re-poisoned before every launch -> prep must run every call.
    prep_kernel<<<23, 256, 0, stream>>>(w_ih0, w_ih_rest, b_ih, b_hh, fc_w, fc_b, ws);

    // 524288 batch / (4 waves * 32 rows) = 4096 blocks
    lstm_mfma<<<4096, 256, 0, stream>>>(x, ws, out);
}